// Round 8
// baseline (208.926 us; speedup 1.0000x reference)
//
#include <hip/hip_runtime.h>

// GIoU loss, 3D boxes, matched pairs, sum-reduced and negated.
// Box row: [x1, y1, x2, y2, z1, z2] (6 f32). Pair of boxes = 48 B = 3 float4.
//
// R1-R6 evidence: five structures (strided direct, global_load_lds+barriers,
// pure-read coalesced probe, quad-ILP direct, nontemporal) all pin at
// 71-80 us for the 192 MB read footprint (~2.6-2.7 TB/s delivered; FETCH_SIZE
// ~96 MB, half served by L3 from the harness input-restore). Pure-read probe
// == compute kernel -> limiter is the cold-miss service path (outstanding-line
// concurrency x ~900cy latency), not kernel structure.
//
// R7/R8 = last untested knob: wave TLP. All prior timed rounds ran 2048
// blocks (8 blocks/CU, occupancy measured only 45-70%). This round: 4096
// blocks (16 blocks/CU queued, 2 grid-stride iters) so the scheduler always
// has ready blocks to backfill ramp/drain. Null result (71-75 us) => declare
// roofline next round. (R7 bench was an infra failure; identical resubmit.)

namespace {

constexpr float kEps     = 1e-7f;
constexpr int   kThreads = 256;     // 4 waves
constexpr int   kBlocks  = 4096;    // 16 blocks/CU queued (was 2048)

__device__ __forceinline__ float giou1(
    float px1, float py1, float px2, float py2, float pz1, float pz2,
    float tx1, float ty1, float tx2, float ty2, float tz1, float tz2)
{
    float vol1 = (px2 - px1) * (py2 - py1) * (pz2 - pz1);
    float vol2 = (tx2 - tx1) * (ty2 - ty1) * (tz2 - tz1);

    float ix = fmaxf(fminf(px2, tx2) - fmaxf(px1, tx1), 0.0f);
    float iy = fmaxf(fminf(py2, ty2) - fmaxf(py1, ty1), 0.0f);
    float iz = fmaxf(fminf(pz2, tz2) - fmaxf(pz1, tz1), 0.0f);
    float inter = ix * iy * iz;
    float uni = vol1 + vol2 - inter;
    float iou = inter / uni;

    float ex = fmaxf(fmaxf(px2, tx2) - fminf(px1, tx1), 0.0f);
    float ey = fmaxf(fmaxf(py2, ty2) - fminf(py1, ty1), 0.0f);
    float ez = fmaxf(fmaxf(pz2, tz2) - fminf(pz1, tz1), 0.0f);
    float enc = ex * ey * ez + kEps;

    return iou - (enc - uni) / enc;
}

__global__ __launch_bounds__(kThreads) void giou_loss_kernel(
    const float* __restrict__ pred, const float* __restrict__ targ,
    float* __restrict__ out, int npairs, int nboxes)
{
    const float4* __restrict__ p4 = reinterpret_cast<const float4*>(pred);
    const float4* __restrict__ t4 = reinterpret_cast<const float4*>(targ);

    double acc = 0.0;
    const int stride = gridDim.x * blockDim.x;
    for (int i = blockIdx.x * blockDim.x + threadIdx.x; i < npairs; i += stride) {
        const size_t b = 3 * (size_t)i;
        float4 pa = p4[b + 0];
        float4 pb = p4[b + 1];
        float4 pc = p4[b + 2];
        float4 ta = t4[b + 0];
        float4 tb = t4[b + 1];
        float4 tc = t4[b + 2];

        // box 2i  : x1=a.x y1=a.y x2=a.z y2=a.w z1=b.x z2=b.y
        // box 2i+1: x1=b.z y1=b.w x2=c.x y2=c.y z1=c.z z2=c.w
        float g0 = giou1(pa.x, pa.y, pa.z, pa.w, pb.x, pb.y,
                         ta.x, ta.y, ta.z, ta.w, tb.x, tb.y);
        float g1 = giou1(pb.z, pb.w, pc.x, pc.y, pc.z, pc.w,
                         tb.z, tb.w, tc.x, tc.y, tc.z, tc.w);
        acc += (double)g0 + (double)g1;
    }

    // Defensive odd-box tail (dead for N = 4e6).
    if ((nboxes & 1) && blockIdx.x == 0 && threadIdx.x == 0) {
        const float* pp = pred + (size_t)(nboxes - 1) * 6;
        const float* tt = targ + (size_t)(nboxes - 1) * 6;
        acc += (double)giou1(pp[0], pp[1], pp[2], pp[3], pp[4], pp[5],
                             tt[0], tt[1], tt[2], tt[3], tt[4], tt[5]);
    }

    // Wave (64-lane) butterfly, then cross-wave via LDS.
    #pragma unroll
    for (int off = 32; off > 0; off >>= 1)
        acc += __shfl_down(acc, off, 64);

    __shared__ double smem[kThreads / 64];
    const int lane = threadIdx.x & 63;
    const int wid  = threadIdx.x >> 6;
    if (lane == 0) smem[wid] = acc;
    __syncthreads();
    if (threadIdx.x == 0) {
        double s = 0.0;
        #pragma unroll
        for (int w = 0; w < kThreads / 64; ++w) s += smem[w];
        // LOSS_WEIGHT * -1 * sum; device-scope atomic (G12), one per block.
        atomicAdd(out, (float)(-s));
    }
}

}  // namespace

extern "C" void kernel_launch(void* const* d_in, const int* in_sizes, int n_in,
                              void* d_out, int out_size, void* d_ws, size_t ws_size,
                              hipStream_t stream) {
    const float* pred = (const float*)d_in[0];
    const float* targ = (const float*)d_in[1];
    float* out = (float*)d_out;

    const int nboxes = in_sizes[0] / 6;    // 4,000,000
    const int npairs = nboxes / 2;         // 2,000,000

    // d_out is re-poisoned to 0xAA before every timed replay: zero it on
    // stream each call (memset nodes are supported in graph capture).
    (void)hipMemsetAsync(out, 0, sizeof(float), stream);

    giou_loss_kernel<<<kBlocks, kThreads, 0, stream>>>(
        pred, targ, out, npairs, nboxes);
}